// Round 12
// baseline (584.184 us; speedup 1.0000x reference)
//
#include <hip/hip_runtime.h>

// HiddenMarkovGFormulaV2: N independent sequential filters over T=64 steps.
// Memory-bound streaming problem (~354 MB HBM traffic w/ L3 reuse).
//
// v13: full-lane scan. v9-v12 wasted lanes 32-63 (scan duplicates) -- a
// wave64 VALU op costs 2 cyc regardless of useful lanes, so serving 64
// rows per wave instead of 32 halves total VALU work (floor 55->27 us)
// and doubles each wave's memory-duty fraction (the duty-cycle lever,
// without compiler-fought prefetch: v11/v12 proved hipcc sinks register
// prefetch across the scan; VGPR stayed 120 both rounds).
//
// LDS for a 64-row panel would need 32 KB (in+var) -> only 5 blocks/CU.
// Instead: ONE 16 KB buffer, reused across phases:
//   stage packed input -> sIM | scan: read sIM, mean -> sIM in place,
//   var -> 64 statically-indexed scalar regs (full 64-step unroll; all
//   indices compile-time -> registers, no scratch) | mean readback +
//   dense store | var regs -> sIM (buffer now free) | var readback +
//   dense store.  10 blocks/CU (LDS-capped), 6250 one-wave blocks.
//
//  * Every global load/store instruction: 64 lanes x 16 B = 1024 B dense.
//  * col = r ^ (t&31) swizzle: all LDS phases <=2-way (free); scan read/
//    write is a lane permutation per 32-half.
//  * S->bit30 / Y->bit31 / C->bits0..29 packed single-word input LDS.
//  * launch_bounds(64,3): VGPR cap 170 >= ~140 live -> no spill
//    (verify: WRITE ~200 MB; any >>210 MB = spilled = probe void).
//  * ll: per-block partial -> d_ws -> tiny reduce kernel (no atomics).
//  * Step math identical v3..v12 (passed, absmax 0.0078125).

#define TT 64          // timesteps (fixed by reference)
#define KK 3           // covariates (fixed by reference)
#define NR 64          // rows per block == lanes (full-lane scan)
#define BT 64          // threads per block (1 wave)

__global__ __launch_bounds__(256) void ll_reduce_kernel(
    const float* __restrict__ part, float* __restrict__ ll_out, int nw)
{
    float s = 0.0f;
    for (int i = threadIdx.x; i < nw; i += 256) s += part[i];
    #pragma unroll
    for (int off = 32; off > 0; off >>= 1) s += __shfl_down(s, off, 64);
    __shared__ float ws[4];
    const int wid = threadIdx.x >> 6, lane = threadIdx.x & 63;
    if (lane == 0) ws[wid] = s;
    __syncthreads();
    if (threadIdx.x == 0) *ll_out = ws[0] + ws[1] + ws[2] + ws[3];
}

// pack S (binary), Y (binary), C (in [0,1)): w = bits(C) | Y<<31 | S<<30.
// Exact: bits(1.0f)<<8 == 0x80000000 (Y); bit23 of 1.0f <<7 -> bit30 (S);
// bits(C) for C in [0,1) never touches bits 30/31.
__device__ __forceinline__ float packSCY(float s, float c, float y) {
    const unsigned w = __float_as_uint(c)
                     | (__float_as_uint(y) << 8)
                     | ((__float_as_uint(s) & 0x00800000u) << 7);
    return __uint_as_float(w);
}

__global__ __launch_bounds__(BT, 3) void hmm_filter_kernel(
    const float* __restrict__ G,   // (N,1)
    const float* __restrict__ S,   // (N,T)
    const float* __restrict__ C,   // (N,T)
    const float* __restrict__ Y,   // (N,T)
    const float* __restrict__ L,   // (N,K)
    const float* __restrict__ p_psi,
    const float* __restrict__ p_gS,
    const float* __restrict__ p_gC,
    const float* __restrict__ p_gG,
    const float* __restrict__ p_gGS,
    const float* __restrict__ p_gGC,
    const float* __restrict__ p_gLw,  // (1,K)
    const float* __restrict__ p_lsZ,
    const float* __restrict__ p_b0,
    const float* __restrict__ p_bZ,
    const float* __restrict__ p_bS,
    const float* __restrict__ p_bG,
    const float* __restrict__ p_bGS,
    const float* __restrict__ p_bLw,  // (1,K)
    float* __restrict__ Zf,           // (N,T)
    float* __restrict__ Zv,           // (N,T)
    float* __restrict__ ll_part,      // one partial per block
    int N)
{
    // [t][col], col = r ^ (t&31). ONE buffer, 16,384 B, phase-reused:
    // packed input -> mean (in-place) -> var (after mean drained).
    __shared__ float sIM[TT][NR];

    const int tid = threadIdx.x;      // 0..63 == lane == row within panel
    const int n0  = blockIdx.x * NR;
    const int n   = n0 + tid;
    const bool valid = (n < N);

    // --- uniform parameters (scalar-cached broadcast loads) ---
    const float psi  = p_psi[0];
    const float gS   = p_gS[0];
    const float gC   = p_gC[0];
    const float gG   = p_gG[0];
    const float gGS  = p_gGS[0];
    const float gGC  = p_gGC[0];
    const float b0   = p_b0[0];
    const float bZ   = p_bZ[0];
    const float bS   = p_bS[0];
    const float bG   = p_bG[0];
    const float bGS  = p_bGS[0];
    const float esz  = expf(p_lsZ[0]);
    const float sigma2 = esz * esz;
    const float psi2 = psi * psi;
    const float bZ2  = bZ * bZ;
    const float gw0 = p_gLw[0], gw1 = p_gLw[1], gw2 = p_gLw[2];
    const float bw0 = p_bLw[0], bw1 = p_bLw[1], bw2 = p_bLw[2];

    // --- per-n constants: fold G and L into per-thread coefficients ---
    float a_s = 0.0f, a_c = 0.0f, zbase = 0.0f, b_s = 0.0f, lbase = 0.0f;
    if (valid) {
        const float Gv = G[n];
        const float l0 = L[n * KK + 0];
        const float l1 = L[n * KK + 1];
        const float l2 = L[n * KK + 2];
        const float gL = l0 * gw0 + l1 * gw1 + l2 * gw2;
        const float bL = l0 * bw0 + l1 * bw1 + l2 * bw2;
        a_s   = gS + gGS * Gv;           // coeff of S_t in transition
        a_c   = gC + gGC * Gv;           // coeff of C_t in transition
        zbase = gG * Gv + gL;            // constant transition term
        b_s   = bS + bGS * Gv;           // coeff of S_t in logit
        lbase = b0 + bG * Gv + bL;       // constant logit term
    } else {
        lbase = b0;                      // keep math finite for dead lanes
    }

    const float4* S4 = (const float4*)S;
    const float4* C4 = (const float4*)C;
    const float4* Y4 = (const float4*)Y;
    float4* Zf4 = (float4*)Zf;
    float4* Zv4 = (float4*)Zv;

    // ---- dense cooperative load + packed swizzled LDS transpose ----
    // Panel = 64 rows x 64 t per array = 1024 float4s; q = tid + i*64:
    // each instruction covers 64 consecutive float4s = 1024 B contiguous.
    #pragma unroll
    for (int i = 0; i < 16; ++i) {
        const int q  = tid + i * BT;
        const int r  = q >> 4;           // 0..63
        const int x  = q & 15;           // float4 within the row
        const int nn = n0 + r;
        float4 vs, vc, vy;
        if (nn < N) {
            const int g = nn * (TT / 4) + x;
            vs = S4[g]; vc = C4[g]; vy = Y4[g];
        } else {
            vs = make_float4(0, 0, 0, 0);
            vc = vs; vy = vs;
        }
        const int t0 = x * 4;
        sIM[t0 + 0][r ^ ((t0 + 0) & 31)] = packSCY(vs.x, vc.x, vy.x);
        sIM[t0 + 1][r ^ ((t0 + 1) & 31)] = packSCY(vs.y, vc.y, vy.y);
        sIM[t0 + 2][r ^ ((t0 + 2) & 31)] = packSCY(vs.z, vc.z, vy.z);
        sIM[t0 + 3][r ^ ((t0 + 3) & 31)] = packSCY(vs.w, vc.w, vy.w);
    }
    asm volatile("s_waitcnt lgkmcnt(0)" ::: "memory");
    __builtin_amdgcn_wave_barrier();   // lanes lockstep; ordering only

    // ---- sequential filter: lane tid owns row tid (ALL 64 lanes) ----
    // Mean overwrites the consumed input slot; var -> static scalar regs.
    float va[TT];                      // 64 regs, all indices static
    float zm = 0.0f, zv = 1.0f, ll2 = 0.0f;

    #pragma unroll
    for (int t = 0; t < TT; ++t) {
        const int col    = tid ^ (t & 31);   // lane perm per 32-half: free
        const unsigned w = __float_as_uint(sIM[t][col]);
        const float c    = __uint_as_float(w & 0x3FFFFFFFu);
        const float s    = (w & 0x40000000u) ? 1.0f : 0.0f;
        const bool  yb   = (w >> 31) != 0u;

        const float zpred = fmaf(psi, zm, fmaf(a_s, s, fmaf(a_c, c, zbase)));
        const float zpvar = fmaf(psi2, zv, sigma2);

        float logit = fmaf(bZ, zpred, fmaf(b_s, s, lbase));
        logit = fminf(fmaxf(logit, -20.0f), 20.0f);
        const float pr  = __builtin_amdgcn_rcpf(1.0f + __expf(-logit));
        const float omp = 1.0f - pr;

        const float ymp = yb ? omp : -pr;    // (y - p)
        const float sel = yb ? pr : omp;     // prob of observed outcome

        const float hess = fmaf(bZ2 * pr, omp, 1e-6f);
        const float zpostvar  = zpvar * __builtin_amdgcn_rcpf(fmaf(zpvar, hess, 1.0f));
        const float zpostmean = fmaf(zpostvar * bZ, ymp, zpred);

        ll2 += __log2f(sel + 1e-10f);

        zm = zpostmean;
        zv = zpostvar;
        sIM[t][col] = zpostmean;   // mean reuses consumed input slot
        va[t]       = zpostvar;    // static index -> stays in VGPRs
    }

    asm volatile("s_waitcnt lgkmcnt(0)" ::: "memory");
    __builtin_amdgcn_wave_barrier();

    // ---- mean readback + dense store (1024 B per instruction) ----
    #pragma unroll
    for (int i = 0; i < 16; ++i) {
        const int q  = tid + i * BT;
        const int r  = q >> 4;
        const int x  = q & 15;
        const int nn = n0 + r;
        if (nn < N) {
            const int t0 = x * 4;
            float4 vf;
            vf.x = sIM[t0 + 0][r ^ ((t0 + 0) & 31)];
            vf.y = sIM[t0 + 1][r ^ ((t0 + 1) & 31)];
            vf.z = sIM[t0 + 2][r ^ ((t0 + 2) & 31)];
            vf.w = sIM[t0 + 3][r ^ ((t0 + 3) & 31)];
            Zf4[nn * (TT / 4) + x] = vf;
        }
    }
    // readback ds_reads must retire before var writes overwrite the buffer
    asm volatile("s_waitcnt lgkmcnt(0)" ::: "memory");
    __builtin_amdgcn_wave_barrier();

    // ---- var regs -> sIM (buffer now free); static t indices ----
    #pragma unroll
    for (int t = 0; t < TT; ++t) {
        sIM[t][tid ^ (t & 31)] = va[t];
    }
    asm volatile("s_waitcnt lgkmcnt(0)" ::: "memory");
    __builtin_amdgcn_wave_barrier();

    // ---- var readback + dense store ----
    #pragma unroll
    for (int i = 0; i < 16; ++i) {
        const int q  = tid + i * BT;
        const int r  = q >> 4;
        const int x  = q & 15;
        const int nn = n0 + r;
        if (nn < N) {
            const int t0 = x * 4;
            float4 vv;
            vv.x = sIM[t0 + 0][r ^ ((t0 + 0) & 31)];
            vv.y = sIM[t0 + 1][r ^ ((t0 + 1) & 31)];
            vv.z = sIM[t0 + 2][r ^ ((t0 + 2) & 31)];
            vv.w = sIM[t0 + 3][r ^ ((t0 + 3) & 31)];
            Zv4[nn * (TT / 4) + x] = vv;
        }
    }

    // ---- ll reduction: wave shuffle -> one partial per block ----
    float ll = valid ? ll2 * 0.69314718055994531f : 0.0f;
    #pragma unroll
    for (int off = 32; off > 0; off >>= 1) {
        ll += __shfl_down(ll, off, 64);
    }
    if (tid == 0) ll_part[blockIdx.x] = ll;
}

extern "C" void kernel_launch(void* const* d_in, const int* in_sizes, int n_in,
                              void* d_out, int out_size, void* d_ws, size_t ws_size,
                              hipStream_t stream) {
    const int N = in_sizes[0];  // G is (N,1)

    const float* G   = (const float*)d_in[0];
    const float* S   = (const float*)d_in[1];
    const float* C   = (const float*)d_in[2];
    const float* Y   = (const float*)d_in[3];
    const float* L   = (const float*)d_in[4];
    const float* psi = (const float*)d_in[5];
    const float* gS  = (const float*)d_in[6];
    const float* gC  = (const float*)d_in[7];
    const float* gG  = (const float*)d_in[8];
    const float* gGS = (const float*)d_in[9];
    const float* gGC = (const float*)d_in[10];
    const float* gLw = (const float*)d_in[11];
    const float* lsZ = (const float*)d_in[12];
    const float* b0  = (const float*)d_in[13];
    const float* bZ  = (const float*)d_in[14];
    const float* bS  = (const float*)d_in[15];
    const float* bG  = (const float*)d_in[16];
    const float* bGS = (const float*)d_in[17];
    const float* bLw = (const float*)d_in[18];

    float* out = (float*)d_out;
    float* Zf = out;
    float* Zv = out + (size_t)N * TT;
    float* ll = out + (size_t)2 * N * TT;

    float* ll_part = (float*)d_ws;   // one float per block of workspace

    const int blocks = (N + NR - 1) / NR;
    hmm_filter_kernel<<<blocks, BT, 0, stream>>>(
        G, S, C, Y, L, psi, gS, gC, gG, gGS, gGC, gLw, lsZ,
        b0, bZ, bS, bG, bGS, bLw, Zf, Zv, ll_part, N);
    ll_reduce_kernel<<<1, 256, 0, stream>>>(ll_part, ll, blocks);
}

// Round 13
// 531.446 us; speedup vs baseline: 1.0992x; 1.0992x over previous
//
#include <hip/hip_runtime.h>

// HiddenMarkovGFormulaV2: N independent sequential filters over T=64 steps.
// Memory-bound streaming problem (~354 MB HBM traffic w/ L3 reuse).
//
// v14: full-lane scan with REGISTER-DIRECT output stores. v13's va[64]
// spilled (VGPR 84, +219 MB scratch): hipcc will not hold >~100 VGPR of
// long-lived state. Key realization: in full-lane mode lane tid computes
// row tid's mean AND var in registers every step -- outputs never need
// LDS. Every 4 steps a lane has {m0..m3},{v0..v3} = two float4s at
// ADJACENT addresses in its own row: store directly. LDS = input only
// (packed, 16 KB) -> 10 blocks/CU. Stores are 16 B/lane @ 256 B stride
// (1/4 density per instruction) but v4/v5 measured such writes coalesce
// in L2 (WRITE stayed ~200-215 MB): each lane completes its full 256 B
// row within the ~5k-cycle scan, lines fill before eviction. Stores are
// spread THROUGH the scan -> memory busy during compute (the duty-cycle
// lever, no compiler-fought prefetch).
//
// Combines every measured-positive property inside the ~80-reg envelope:
//  * full-lane (64 rows/wave): VALU floor ~27 us (half of v9-v12)
//  * 16 KB LDS -> 10 blocks/CU; no barriers; no atomics; ~70 VGPR live
//  * dense 1 KB/instruction input loads + packed single-word LDS
//    (S->bit30, Y->bit31, C->bits0..29; exact for S,Y in {0,1}, C<1)
//  * col = r^(t&31) swizzle: stage <=2-way, scan = lane permutation
//  * outputs: zero LDS staging, zero readback phases, zero waits
//  * ll: per-block partial -> d_ws -> tiny reduce (no atomics)
//  * step math identical v3..v13 (passed, absmax 0.0078125)
//
// Pre-committed verification: VGPR 70-100 & WRITE ~200-220 MB (>250 MB =
// store-coalescing failure = void); predict dur 154 -> ~105-130 us.

#define TT 64          // timesteps (fixed by reference)
#define KK 3           // covariates (fixed by reference)
#define NR 64          // rows per block == lanes (full-lane scan)
#define BT 64          // threads per block (1 wave)

__global__ __launch_bounds__(256) void ll_reduce_kernel(
    const float* __restrict__ part, float* __restrict__ ll_out, int nw)
{
    float s = 0.0f;
    for (int i = threadIdx.x; i < nw; i += 256) s += part[i];
    #pragma unroll
    for (int off = 32; off > 0; off >>= 1) s += __shfl_down(s, off, 64);
    __shared__ float ws[4];
    const int wid = threadIdx.x >> 6, lane = threadIdx.x & 63;
    if (lane == 0) ws[wid] = s;
    __syncthreads();
    if (threadIdx.x == 0) *ll_out = ws[0] + ws[1] + ws[2] + ws[3];
}

// pack S (binary), Y (binary), C (in [0,1)): w = bits(C) | Y<<31 | S<<30.
// Exact: bits(1.0f)<<8 == 0x80000000 (Y); bit23 of 1.0f <<7 -> bit30 (S);
// bits(C) for C in [0,1) never touches bits 30/31.
__device__ __forceinline__ float packSCY(float s, float c, float y) {
    const unsigned w = __float_as_uint(c)
                     | (__float_as_uint(y) << 8)
                     | ((__float_as_uint(s) & 0x00800000u) << 7);
    return __uint_as_float(w);
}

// One filter step reading packed word W; writes mean/var to OM/OV.
#define STEP(W, OM, OV)                                                     \
    {                                                                       \
        const unsigned w_ = (W);                                            \
        const float c_  = __uint_as_float(w_ & 0x3FFFFFFFu);                \
        const float s_  = (w_ & 0x40000000u) ? 1.0f : 0.0f;                 \
        const bool  yb_ = (w_ >> 31) != 0u;                                 \
        const float zpred = fmaf(psi, zm, fmaf(a_s, s_, fmaf(a_c, c_, zbase))); \
        const float zpvar = fmaf(psi2, zv, sigma2);                         \
        float logit = fmaf(bZ, zpred, fmaf(b_s, s_, lbase));                \
        logit = fminf(fmaxf(logit, -20.0f), 20.0f);                         \
        const float pr_  = __builtin_amdgcn_rcpf(1.0f + __expf(-logit));    \
        const float omp_ = 1.0f - pr_;                                      \
        const float ymp_ = yb_ ? omp_ : -pr_;                               \
        const float sel_ = yb_ ? pr_ : omp_;                                \
        const float hess_ = fmaf(bZ2 * pr_, omp_, 1e-6f);                   \
        const float zpv_  = zpvar * __builtin_amdgcn_rcpf(fmaf(zpvar, hess_, 1.0f)); \
        const float zpm_  = fmaf(zpv_ * bZ, ymp_, zpred);                   \
        ll2 += __log2f(sel_ + 1e-10f);                                      \
        zm = zpm_;                                                          \
        zv = zpv_;                                                          \
        (OM) = zpm_;                                                        \
        (OV) = zpv_;                                                        \
    }

__global__ __launch_bounds__(BT, 4) void hmm_filter_kernel(
    const float* __restrict__ G,   // (N,1)
    const float* __restrict__ S,   // (N,T)
    const float* __restrict__ C,   // (N,T)
    const float* __restrict__ Y,   // (N,T)
    const float* __restrict__ L,   // (N,K)
    const float* __restrict__ p_psi,
    const float* __restrict__ p_gS,
    const float* __restrict__ p_gC,
    const float* __restrict__ p_gG,
    const float* __restrict__ p_gGS,
    const float* __restrict__ p_gGC,
    const float* __restrict__ p_gLw,  // (1,K)
    const float* __restrict__ p_lsZ,
    const float* __restrict__ p_b0,
    const float* __restrict__ p_bZ,
    const float* __restrict__ p_bS,
    const float* __restrict__ p_bG,
    const float* __restrict__ p_bGS,
    const float* __restrict__ p_bLw,  // (1,K)
    float* __restrict__ Zf,           // (N,T)
    float* __restrict__ Zv,           // (N,T)
    float* __restrict__ ll_part,      // one partial per block
    int N)
{
    // [t][col], col = r ^ (t&31). INPUT ONLY: 16,384 B.
    __shared__ float sIM[TT][NR];

    const int tid = threadIdx.x;      // 0..63 == lane == row within panel
    const int n0  = blockIdx.x * NR;
    const int n   = n0 + tid;
    const bool valid = (n < N);

    // --- uniform parameters (scalar-cached broadcast loads) ---
    const float psi  = p_psi[0];
    const float gS   = p_gS[0];
    const float gC   = p_gC[0];
    const float gG   = p_gG[0];
    const float gGS  = p_gGS[0];
    const float gGC  = p_gGC[0];
    const float b0   = p_b0[0];
    const float bZ   = p_bZ[0];
    const float bS   = p_bS[0];
    const float bG   = p_bG[0];
    const float bGS  = p_bGS[0];
    const float esz  = expf(p_lsZ[0]);
    const float sigma2 = esz * esz;
    const float psi2 = psi * psi;
    const float bZ2  = bZ * bZ;
    const float gw0 = p_gLw[0], gw1 = p_gLw[1], gw2 = p_gLw[2];
    const float bw0 = p_bLw[0], bw1 = p_bLw[1], bw2 = p_bLw[2];

    // --- per-n constants: fold G and L into per-thread coefficients ---
    float a_s = 0.0f, a_c = 0.0f, zbase = 0.0f, b_s = 0.0f, lbase = 0.0f;
    if (valid) {
        const float Gv = G[n];
        const float l0 = L[n * KK + 0];
        const float l1 = L[n * KK + 1];
        const float l2 = L[n * KK + 2];
        const float gL = l0 * gw0 + l1 * gw1 + l2 * gw2;
        const float bL = l0 * bw0 + l1 * bw1 + l2 * bw2;
        a_s   = gS + gGS * Gv;           // coeff of S_t in transition
        a_c   = gC + gGC * Gv;           // coeff of C_t in transition
        zbase = gG * Gv + gL;            // constant transition term
        b_s   = bS + bGS * Gv;           // coeff of S_t in logit
        lbase = b0 + bG * Gv + bL;       // constant logit term
    } else {
        lbase = b0;                      // keep math finite for dead lanes
    }

    const float4* S4 = (const float4*)S;
    const float4* C4 = (const float4*)C;
    const float4* Y4 = (const float4*)Y;
    float4* Zf4 = (float4*)Zf;
    float4* Zv4 = (float4*)Zv;

    // ---- dense cooperative load + packed swizzled LDS transpose ----
    // Panel = 64 rows x 64 t per array = 1024 float4s; q = tid + i*64:
    // each instruction covers 64 consecutive float4s = 1024 B contiguous.
    #pragma unroll
    for (int i = 0; i < 16; ++i) {
        const int q  = tid + i * BT;
        const int r  = q >> 4;           // 0..63
        const int x  = q & 15;           // float4 within the row
        const int nn = n0 + r;
        float4 vs, vc, vy;
        if (nn < N) {
            const int g = nn * (TT / 4) + x;
            vs = S4[g]; vc = C4[g]; vy = Y4[g];
        } else {
            vs = make_float4(0, 0, 0, 0);
            vc = vs; vy = vs;
        }
        const int t0 = x * 4;
        sIM[t0 + 0][r ^ ((t0 + 0) & 31)] = packSCY(vs.x, vc.x, vy.x);
        sIM[t0 + 1][r ^ ((t0 + 1) & 31)] = packSCY(vs.y, vc.y, vy.y);
        sIM[t0 + 2][r ^ ((t0 + 2) & 31)] = packSCY(vs.z, vc.z, vy.z);
        sIM[t0 + 3][r ^ ((t0 + 3) & 31)] = packSCY(vs.w, vc.w, vy.w);
    }
    asm volatile("s_waitcnt lgkmcnt(0)" ::: "memory");
    __builtin_amdgcn_wave_barrier();   // lanes lockstep; ordering only

    // ---- full-lane sequential filter; outputs stored register-direct ----
    // Lane tid owns row tid. Every 4 steps: two float4 stores to the
    // lane's OWN row (adjacent addresses) -- no LDS staging, stores
    // spread through the scan keep memory busy during compute.
    float zm = 0.0f, zv = 1.0f, ll2 = 0.0f;
    const int rowb = n * (TT / 4);       // float4 base of this lane's row

    for (int tg = 0; tg < TT / 4; ++tg) {
        float4 mf, vf;
        const int t = tg * 4;
        STEP(__float_as_uint(sIM[t + 0][tid ^ ((t + 0) & 31)]), mf.x, vf.x);
        STEP(__float_as_uint(sIM[t + 1][tid ^ ((t + 1) & 31)]), mf.y, vf.y);
        STEP(__float_as_uint(sIM[t + 2][tid ^ ((t + 2) & 31)]), mf.z, vf.z);
        STEP(__float_as_uint(sIM[t + 3][tid ^ ((t + 3) & 31)]), mf.w, vf.w);
        if (valid) {
            Zf4[rowb + tg] = mf;
            Zv4[rowb + tg] = vf;
        }
    }

    // ---- ll reduction: wave shuffle -> one partial per block ----
    float ll = valid ? ll2 * 0.69314718055994531f : 0.0f;
    #pragma unroll
    for (int off = 32; off > 0; off >>= 1) {
        ll += __shfl_down(ll, off, 64);
    }
    if (tid == 0) ll_part[blockIdx.x] = ll;
}

extern "C" void kernel_launch(void* const* d_in, const int* in_sizes, int n_in,
                              void* d_out, int out_size, void* d_ws, size_t ws_size,
                              hipStream_t stream) {
    const int N = in_sizes[0];  // G is (N,1)

    const float* G   = (const float*)d_in[0];
    const float* S   = (const float*)d_in[1];
    const float* C   = (const float*)d_in[2];
    const float* Y   = (const float*)d_in[3];
    const float* L   = (const float*)d_in[4];
    const float* psi = (const float*)d_in[5];
    const float* gS  = (const float*)d_in[6];
    const float* gC  = (const float*)d_in[7];
    const float* gG  = (const float*)d_in[8];
    const float* gGS = (const float*)d_in[9];
    const float* gGC = (const float*)d_in[10];
    const float* gLw = (const float*)d_in[11];
    const float* lsZ = (const float*)d_in[12];
    const float* b0  = (const float*)d_in[13];
    const float* bZ  = (const float*)d_in[14];
    const float* bS  = (const float*)d_in[15];
    const float* bG  = (const float*)d_in[16];
    const float* bGS = (const float*)d_in[17];
    const float* bLw = (const float*)d_in[18];

    float* out = (float*)d_out;
    float* Zf = out;
    float* Zv = out + (size_t)N * TT;
    float* ll = out + (size_t)2 * N * TT;

    float* ll_part = (float*)d_ws;   // one float per block of workspace

    const int blocks = (N + NR - 1) / NR;
    hmm_filter_kernel<<<blocks, BT, 0, stream>>>(
        G, S, C, Y, L, psi, gS, gC, gG, gGS, gGC, gLw, lsZ,
        b0, bZ, bS, bG, bGS, bLw, Zf, Zv, ll_part, N);
    ll_reduce_kernel<<<1, 256, 0, stream>>>(ll_part, ll, blocks);
}